// Round 4
// baseline (37.571 us; speedup 1.0000x reference)
//
#include <hip/hip_runtime.h>

// Reference reduction (proven rounds 0-2, absmax 0.0):
//   nn_idx[0] == 0 always  =>  exp_neighbor = exp(relu(features[b,0,:]))
//   gamma[i] = max_c( f_ic * exp(f_ic - f_0c) ) / max_c f_ic,  f = relu(features)
//   out      = gamma / ||gamma||_2 per cloud, concatenated.  coords are dead.
//
// Single cooperative dispatch with a HAND-ROLLED device-scope barrier
// (cg::this_grid().sync() measured ~25us on gfx950 -- round 3 post-mortem).
// gamma stays in registers across the barrier; out written exactly once.
// Barrier counter lives in d_ws and is zeroed by a memset node each call
// (d_ws is poisoned 0xAA before timing, so no leftover-state assumptions).
// Happens-before: partial store (relaxed,agent) -> fetch_add(release,agent)
// -> spin load(acquire,agent) == NBLOCKS -> partial loads (relaxed,agent).

static constexpr int NPTS = 12288;
static constexpr int CCH  = 32;
static constexpr int BLK  = 256;
static constexpr int NBLK = NPTS / BLK;          // 48 blocks per cloud
static constexpr int CTR_OFF = 512;              // byte offset of counter in d_ws

__global__ void __launch_bounds__(BLK) fused_kernel(const float* __restrict__ feats,
                                                    float* __restrict__ out,
                                                    float* __restrict__ partials,
                                                    unsigned* __restrict__ counter,
                                                    int nblocks_total) {
    const int b = blockIdx.y;
    const float* base = feats + (size_t)b * NPTS * CCH;

    // relu(f[0,:]) — wave-uniform address -> scalar loads, L1-resident.
    float f0[CCH];
#pragma unroll
    for (int q = 0; q < CCH / 4; ++q) {
        float4 v = reinterpret_cast<const float4*>(base)[q];
        f0[4 * q + 0] = fmaxf(v.x, 0.0f);
        f0[4 * q + 1] = fmaxf(v.y, 0.0f);
        f0[4 * q + 2] = fmaxf(v.z, 0.0f);
        f0[4 * q + 3] = fmaxf(v.w, 0.0f);
    }

    const int i = blockIdx.x * BLK + threadIdx.x;
    const float4* row = reinterpret_cast<const float4*>(base + (size_t)i * CCH);

    float fm = 0.0f, g = 0.0f;
#pragma unroll
    for (int q = 0; q < CCH / 4; ++q) {
        float4 v = row[q];
        float x0 = fmaxf(v.x, 0.0f), x1 = fmaxf(v.y, 0.0f);
        float x2 = fmaxf(v.z, 0.0f), x3 = fmaxf(v.w, 0.0f);
        fm = fmaxf(fm, fmaxf(fmaxf(x0, x1), fmaxf(x2, x3)));
        g = fmaxf(g, x0 * __expf(x0 - f0[4 * q + 0]));
        g = fmaxf(g, x1 * __expf(x1 - f0[4 * q + 1]));
        g = fmaxf(g, x2 * __expf(x2 - f0[4 * q + 2]));
        g = fmaxf(g, x3 * __expf(x3 - f0[4 * q + 3]));
    }
    const float gamma = g / fm;  // stays in a register across the barrier

    // Deterministic block reduction of gamma^2 (fixed shuffle + LDS order).
    float s = gamma * gamma;
#pragma unroll
    for (int off = 32; off > 0; off >>= 1) s += __shfl_down(s, off);
    __shared__ float red[BLK / 64];
    const int lane = threadIdx.x & 63;
    const int wv   = threadIdx.x >> 6;
    if (lane == 0) red[wv] = s;
    __syncthreads();

    if (threadIdx.x == 0) {
        float p = (red[0] + red[1]) + (red[2] + red[3]);
        __hip_atomic_store(&partials[b * NBLK + blockIdx.x], p,
                           __ATOMIC_RELAXED, __HIP_MEMORY_SCOPE_AGENT);
        // arrive (release: publishes the partial store above)
        __hip_atomic_fetch_add(counter, 1u,
                               __ATOMIC_RELEASE, __HIP_MEMORY_SCOPE_AGENT);
        // wait for all blocks (acquire: makes all partials visible)
        while (__hip_atomic_load(counter, __ATOMIC_ACQUIRE,
                                 __HIP_MEMORY_SCOPE_AGENT) < (unsigned)nblocks_total)
            __builtin_amdgcn_s_sleep(2);
    }
    __syncthreads();

    // Fixed-order sum of the 48 partials: deterministic across all blocks.
    float t = 0.0f;
#pragma unroll
    for (int j = 0; j < NBLK; ++j)
        t += __hip_atomic_load(&partials[b * NBLK + j],
                               __ATOMIC_RELAXED, __HIP_MEMORY_SCOPE_AGENT);

    out[(size_t)b * NPTS + i] = gamma * rsqrtf(t);
}

extern "C" void kernel_launch(void* const* d_in, const int* in_sizes, int n_in,
                              void* d_out, int out_size, void* d_ws, size_t ws_size,
                              hipStream_t stream) {
    const float* feats = (const float*)d_in[1];  // features [B,N,C] f32; coords dead
    float* out = (float*)d_out;                  // [B*N] f32
    float* partials = (float*)d_ws;              // [B,48] f32, fully rewritten every call
    unsigned* counter = (unsigned*)((char*)d_ws + CTR_OFF);

    const int B = out_size / NPTS;
    int nblocks_total = NBLK * B;

    // Zero the barrier counter every call (memset node in the graph).
    hipMemsetAsync(counter, 0, sizeof(unsigned), stream);

    dim3 grid(NBLK, B), block(BLK);
    void* args[] = {(void*)&feats, (void*)&out, (void*)&partials,
                    (void*)&counter, (void*)&nblocks_total};
    hipLaunchCooperativeKernel(reinterpret_cast<void*>(fused_kernel),
                               grid, block, args, 0, stream);
}

// Round 5
// 17.674 us; speedup vs baseline: 2.1258x; 2.1258x over previous
//
#include <hip/hip_runtime.h>

// Reference reduction (proven rounds 0-4, absmax 0.0):
//   nn_idx[0] == 0 always  =>  exp_neighbor = exp(relu(features[b,0,:]))
//   gamma[i] = max_c( f_ic * exp(f_ic - f_0c) ) / max_c f_ic,  f = relu(features)
//   out      = gamma / ||gamma||_2 per cloud, concatenated.  coords are dead.
//
// Round-4 post-mortem: the hipLaunchCooperativeKernel NODE costs ~25us in
// graph replay (coop+cg::sync 35.5us ~= coop+hand-barrier 37.6us). The spin
// barrier itself is cheap. So: PLAIN launch + hand-rolled device-scope
// barrier. Co-residency by construction: 96 blocks x 256 thr (4 waves,
// ~32 VGPR, 16B LDS) <= 1 block/CU on 256 CUs -- all blocks resident at
// dispatch, spin cannot deadlock.
//
// Counter zeroed by a 4-byte memset node each call (d_ws poisoned 0xAA once
// before timing; no reliance on leftover state). Happens-before chain:
// partial store (relaxed,agent) -> fetch_add(release,agent) -> spin
// load(acquire,agent)==96 -> partial loads (relaxed,agent). Post-barrier sum
// is fixed-order 48 terms -> bitwise deterministic.

static constexpr int NPTS = 12288;
static constexpr int CCH  = 32;
static constexpr int BLK  = 256;
static constexpr int NBLK = NPTS / BLK;          // 48 blocks per cloud
static constexpr int CTR_OFF = 512;              // byte offset of counter in d_ws

__global__ void __launch_bounds__(BLK) fused_kernel(const float* __restrict__ feats,
                                                    float* __restrict__ out,
                                                    float* __restrict__ partials,
                                                    unsigned* __restrict__ counter,
                                                    int nblocks_total) {
    const int b = blockIdx.y;
    const float* base = feats + (size_t)b * NPTS * CCH;

    // relu(f[0,:]) — wave-uniform address -> scalar loads, L1-resident.
    float f0[CCH];
#pragma unroll
    for (int q = 0; q < CCH / 4; ++q) {
        float4 v = reinterpret_cast<const float4*>(base)[q];
        f0[4 * q + 0] = fmaxf(v.x, 0.0f);
        f0[4 * q + 1] = fmaxf(v.y, 0.0f);
        f0[4 * q + 2] = fmaxf(v.z, 0.0f);
        f0[4 * q + 3] = fmaxf(v.w, 0.0f);
    }

    const int i = blockIdx.x * BLK + threadIdx.x;
    const float4* row = reinterpret_cast<const float4*>(base + (size_t)i * CCH);

    float fm = 0.0f, g = 0.0f;
#pragma unroll
    for (int q = 0; q < CCH / 4; ++q) {
        float4 v = row[q];
        float x0 = fmaxf(v.x, 0.0f), x1 = fmaxf(v.y, 0.0f);
        float x2 = fmaxf(v.z, 0.0f), x3 = fmaxf(v.w, 0.0f);
        fm = fmaxf(fm, fmaxf(fmaxf(x0, x1), fmaxf(x2, x3)));
        g = fmaxf(g, x0 * __expf(x0 - f0[4 * q + 0]));
        g = fmaxf(g, x1 * __expf(x1 - f0[4 * q + 1]));
        g = fmaxf(g, x2 * __expf(x2 - f0[4 * q + 2]));
        g = fmaxf(g, x3 * __expf(x3 - f0[4 * q + 3]));
    }
    const float gamma = g / fm;  // stays in a register across the barrier

    // Deterministic block reduction of gamma^2 (fixed shuffle + LDS order).
    float s = gamma * gamma;
#pragma unroll
    for (int off = 32; off > 0; off >>= 1) s += __shfl_down(s, off);
    __shared__ float red[BLK / 64];
    const int lane = threadIdx.x & 63;
    const int wv   = threadIdx.x >> 6;
    if (lane == 0) red[wv] = s;
    __syncthreads();

    if (threadIdx.x == 0) {
        float p = (red[0] + red[1]) + (red[2] + red[3]);
        __hip_atomic_store(&partials[b * NBLK + blockIdx.x], p,
                           __ATOMIC_RELAXED, __HIP_MEMORY_SCOPE_AGENT);
        // arrive (release: publishes the partial store above)
        __hip_atomic_fetch_add(counter, 1u,
                               __ATOMIC_RELEASE, __HIP_MEMORY_SCOPE_AGENT);
        // wait for all blocks (acquire: makes all partials visible)
        while (__hip_atomic_load(counter, __ATOMIC_ACQUIRE,
                                 __HIP_MEMORY_SCOPE_AGENT) < (unsigned)nblocks_total)
            __builtin_amdgcn_s_sleep(2);
    }
    __syncthreads();

    // Fixed-order sum of the 48 partials: deterministic across all blocks.
    float t = 0.0f;
#pragma unroll
    for (int j = 0; j < NBLK; ++j)
        t += __hip_atomic_load(&partials[b * NBLK + j],
                               __ATOMIC_RELAXED, __HIP_MEMORY_SCOPE_AGENT);

    out[(size_t)b * NPTS + i] = gamma * rsqrtf(t);
}

extern "C" void kernel_launch(void* const* d_in, const int* in_sizes, int n_in,
                              void* d_out, int out_size, void* d_ws, size_t ws_size,
                              hipStream_t stream) {
    const float* feats = (const float*)d_in[1];  // features [B,N,C] f32; coords dead
    float* out = (float*)d_out;                  // [B*N] f32
    float* partials = (float*)d_ws;              // [B,48] f32, fully rewritten every call
    unsigned* counter = (unsigned*)((char*)d_ws + CTR_OFF);

    const int B = out_size / NPTS;
    const int nblocks_total = NBLK * B;

    // Zero the barrier counter every call (4-byte memset node in the graph).
    hipMemsetAsync(counter, 0, sizeof(unsigned), stream);

    dim3 grid(NBLK, B);
    fused_kernel<<<grid, BLK, 0, stream>>>(feats, out, partials, counter,
                                           nblocks_total);
}

// Round 6
// 12.006 us; speedup vs baseline: 3.1294x; 1.4721x over previous
//
#include <hip/hip_runtime.h>

// Reference reduction (proven rounds 0-5, absmax 0.0):
//   nn_idx[0] == 0 always  =>  exp_neighbor = exp(relu(features[b,0,:]))
//   gamma[i] = max_c( f_ic * exp(f_ic - f_0c) ) / max_c f_ic,  f = relu(features)
//   out      = gamma / ||gamma||_2 per cloud, concatenated.  coords are dead.
//
// Structure (round-2, best measured: 11.8 us):
//   kernel1: gamma + deterministic per-block partial sum(gamma^2) -> d_ws
//   kernel2: fixed-order sum of 48 partials (uniform scalar loads) + scale
// Session evidence for this structure being the floor:
//   - cooperative launch node: +25 us (rounds 3/4)
//   - in-kernel device-scope barrier (plain launch + memset node): 17.7 us
//     (round 5) -- cross-XCD hot-line atomics cost more than a dispatch
//   - real memory work is ~1 us; remainder is per-node graph-replay overhead

static constexpr int NPTS = 12288;
static constexpr int CCH  = 32;
static constexpr int BLK  = 256;
static constexpr int NBLK = NPTS / BLK;  // 48 blocks per cloud

__global__ void __launch_bounds__(BLK) gamma_kernel(const float* __restrict__ feats,
                                                    float* __restrict__ out,
                                                    float* __restrict__ partials) {
    const int b = blockIdx.y;
    const float* base = feats + (size_t)b * NPTS * CCH;

    // relu(f[0,:]) — wave-uniform address, compiler scalarizes; L1-resident.
    float f0[CCH];
#pragma unroll
    for (int q = 0; q < CCH / 4; ++q) {
        float4 v = reinterpret_cast<const float4*>(base)[q];
        f0[4 * q + 0] = fmaxf(v.x, 0.0f);
        f0[4 * q + 1] = fmaxf(v.y, 0.0f);
        f0[4 * q + 2] = fmaxf(v.z, 0.0f);
        f0[4 * q + 3] = fmaxf(v.w, 0.0f);
    }

    const int i = blockIdx.x * BLK + threadIdx.x;
    const float4* row = reinterpret_cast<const float4*>(base + (size_t)i * CCH);

    float fm = 0.0f, g = 0.0f;
#pragma unroll
    for (int q = 0; q < CCH / 4; ++q) {
        float4 v = row[q];
        float x0 = fmaxf(v.x, 0.0f), x1 = fmaxf(v.y, 0.0f);
        float x2 = fmaxf(v.z, 0.0f), x3 = fmaxf(v.w, 0.0f);
        fm = fmaxf(fm, fmaxf(fmaxf(x0, x1), fmaxf(x2, x3)));
        g = fmaxf(g, x0 * __expf(x0 - f0[4 * q + 0]));
        g = fmaxf(g, x1 * __expf(x1 - f0[4 * q + 1]));
        g = fmaxf(g, x2 * __expf(x2 - f0[4 * q + 2]));
        g = fmaxf(g, x3 * __expf(x3 - f0[4 * q + 3]));
    }

    const float gamma = g / fm;
    out[(size_t)b * NPTS + i] = gamma;

    // Deterministic block reduction of gamma^2 (fixed shuffle + LDS order).
    float s = gamma * gamma;
#pragma unroll
    for (int off = 32; off > 0; off >>= 1) s += __shfl_down(s, off);
    __shared__ float red[BLK / 64];
    const int lane = threadIdx.x & 63;
    const int wv   = threadIdx.x >> 6;
    if (lane == 0) red[wv] = s;
    __syncthreads();
    if (threadIdx.x == 0)
        partials[b * NBLK + blockIdx.x] = ((red[0] + red[1]) + (red[2] + red[3]));
}

__global__ void __launch_bounds__(BLK) scale_kernel(float* __restrict__ out,
                                                    const float* __restrict__ partials) {
    const int b = blockIdx.y;
    // Fixed-order serial sum of 48 partials: uniform (scalar) loads, deterministic.
    float t = 0.0f;
#pragma unroll
    for (int j = 0; j < NBLK; ++j) t += partials[b * NBLK + j];
    const float sc = rsqrtf(t);

    const int i = blockIdx.x * BLK + threadIdx.x;
    out[(size_t)b * NPTS + i] *= sc;
}

extern "C" void kernel_launch(void* const* d_in, const int* in_sizes, int n_in,
                              void* d_out, int out_size, void* d_ws, size_t ws_size,
                              hipStream_t stream) {
    const float* feats = (const float*)d_in[1];  // features [B,N,C] f32; coords dead
    float* out = (float*)d_out;                  // [B*N] f32
    float* partials = (float*)d_ws;              // [B,48] f32, rewritten every call

    const int B = out_size / NPTS;
    dim3 grid(NBLK, B);
    gamma_kernel<<<grid, BLK, 0, stream>>>(feats, out, partials);
    scale_kernel<<<grid, BLK, 0, stream>>>(out, partials);
}